// Round 2
// baseline (15079.678 us; speedup 1.0000x reference)
//
#include <hip/hip_runtime.h>
#include <math.h>

// GMM EM, 10 stages, N=65536 D=128 K=16, fp32.
// out = BETA*(z@means_f) + X ; z = memberships from stage 10 E-step.
// Strategy: all heavy matmuls are fp32 VALU with one wave-uniform operand
// (scalar s_load stream) and per-lane data in VGPRs; no fp32 MFMA exists on CDNA4.

#define NPTS 65536
#define DIM 128
#define KC 16
#define STAGES 10
#define BETA_C 3.0f
#define EPS_C 1e-6f
#define NCH 32
#define NTILES 6
#define CHUNK (NPTS / NCH)

// ---------------------------------------------------------------------------
// prep: per-component Cholesky of (cov + eps I), blocked triangular inverse
// W = L^-1, m = W*mu, kconst = -0.5*logdet. 16 blocks x 256 thr, 149KB LDS.
// ---------------------------------------------------------------------------
__global__ __launch_bounds__(256) void prep_kernel(
    const float* __restrict__ covs, const float* __restrict__ means,
    float* __restrict__ W4, float* __restrict__ mvec, float* __restrict__ kconst)
{
  extern __shared__ float smem[];
  float (*A)[DIM + 1]  = (float (*)[DIM + 1])smem;            // 128*129
  float (*Wv)[DIM + 1] = (float (*)[DIM + 1])(smem + 16512);  // 128*129
  float (*T)[65]       = (float (*)[65])(smem + 33024);       // 64*65
  float* red = smem + 37184;                                  // 128

  const int k = blockIdx.x;
  const int t = threadIdx.x;
  const int tr = t & 127;
  const int th = t >> 7;
  const float* C = covs + (size_t)k * DIM * DIM;

  for (int i = th; i < DIM; i += 2) {
    float v = C[(size_t)i * DIM + tr];
    if (i == tr) v += EPS_C;
    A[i][tr] = v;
    Wv[i][tr] = 0.0f;
  }
  __syncthreads();

  // Cholesky (right-looking, lower triangle in place)
  for (int j = 0; j < DIM; ++j) {
    if (t == 0) A[j][j] = sqrtf(A[j][j]);
    __syncthreads();
    const float Ljj = A[j][j];
    if (th == 0 && tr > j) A[tr][j] /= Ljj;
    __syncthreads();
    if (tr > j) {
      const float aij = A[tr][j];
      for (int l = j + 1 + th; l <= tr; l += 2)
        A[tr][l] -= aij * A[l][j];
    }
    __syncthreads();
  }

  // blocked inverse: W11=L11^-1, W22=L22^-1 (parallel), W21=-W22*(L21*W11)
  if (t < DIM) {
    const int g = t >> 6, c = t & 63, o = g * 64;
    Wv[o + c][o + c] = 1.0f / A[o + c][o + c];
    for (int i = c + 1; i < 64; ++i) {
      float s = 0.0f;
      for (int p = c; p < i; ++p) s += A[o + i][o + p] * Wv[o + p][o + c];
      Wv[o + i][o + c] = -s / A[o + i][o + i];
    }
  }
  __syncthreads();
  for (int idx = t; idx < 4096; idx += 256) {
    const int i = idx >> 6, c = idx & 63;
    float s = 0.0f;
    for (int p = c; p < 64; ++p) s += A[64 + i][p] * Wv[p][c];
    T[i][c] = s;
  }
  __syncthreads();
  for (int idx = t; idx < 4096; idx += 256) {
    const int i = idx >> 6, c = idx & 63;
    float s = 0.0f;
    for (int p = 0; p <= i; ++p) s += Wv[64 + i][64 + p] * T[p][c];
    Wv[64 + i][c] = -s;
  }
  __syncthreads();

  if (t < DIM) {
    const float* mu = means + k * DIM;
    float s = 0.0f;
    for (int e = 0; e <= t; ++e) s += Wv[t][e] * mu[e];
    mvec[k * DIM + t] = s;
    red[t] = logf(A[t][t]);
  }
  __syncthreads();
  if (t == 0) {
    float s = 0.0f;
    for (int i = 0; i < DIM; ++i) s += red[i];
    kconst[k] = -s;  // == -0.5 * logdet
  }
  // W stored interleaved: W4[((k*32+db)*128+e)*4 + j] = W[4*db+j][e]
  for (int idx = t; idx < DIM * DIM; idx += 256) {
    const int d = idx >> 7, e = idx & 127;
    W4[(((size_t)k * 32 + (d >> 2)) * DIM + e) * 4 + (d & 3)] = Wv[d][e];
  }
}

// ---------------------------------------------------------------------------
// estep: z[n][k] = softmax_k( -0.5*logdet_k - 0.5*||W_k x_n - m_k||^2 )
// Block = 128 thr (2 waves); 64 rows/block, x-row in VGPRs (static indexing),
// wave w handles k in [8w, 8w+8). W streamed via scalar loads (wave-uniform).
// Triangular e-range via switch fallthrough (keeps x[] register-resident).
// ---------------------------------------------------------------------------
#define ECHUNK(EB)                                      \
  _Pragma("unroll")                                     \
  for (int e = (EB) * 16; e < (EB) * 16 + 16; ++e) {    \
    const float xe = x[e];                              \
    y0 = fmaf(xe, Wr4[4 * e + 0], y0);                  \
    y1 = fmaf(xe, Wr4[4 * e + 1], y1);                  \
    y2 = fmaf(xe, Wr4[4 * e + 2], y2);                  \
    y3 = fmaf(xe, Wr4[4 * e + 3], y3);                  \
  }

__global__ __launch_bounds__(128) void estep_kernel(
    const float* __restrict__ X, const float* __restrict__ W4,
    const float* __restrict__ mvec, const float* __restrict__ kconst,
    float* __restrict__ Z)
{
  __shared__ float lp[64][KC + 1];
  const int lane = threadIdx.x & 63;
  const int w = __builtin_amdgcn_readfirstlane(threadIdx.x >> 6);
  const int row = blockIdx.x * 64 + lane;

  float x[DIM];
  const float4* xr = (const float4*)(X + (size_t)row * DIM);
#pragma unroll
  for (int j = 0; j < DIM / 4; ++j) {
    const float4 v = xr[j];
    x[4 * j + 0] = v.x; x[4 * j + 1] = v.y;
    x[4 * j + 2] = v.z; x[4 * j + 3] = v.w;
  }

  for (int kk = 0; kk < KC / 2; ++kk) {
    const int k = w * (KC / 2) + kk;
    const float* __restrict__ mk = mvec + k * DIM;
    float maha = 0.0f;
    for (int db = 0; db < DIM / 4; ++db) {
      const float* __restrict__ Wr4 = W4 + ((size_t)k * 32 + db) * DIM * 4;
      float y0 = 0.0f, y1 = 0.0f, y2 = 0.0f, y3 = 0.0f;
      switch (db >> 2) {            // rows 4db..4db+3 need e <= 4db+3
        case 7: ECHUNK(7) [[fallthrough]];
        case 6: ECHUNK(6) [[fallthrough]];
        case 5: ECHUNK(5) [[fallthrough]];
        case 4: ECHUNK(4) [[fallthrough]];
        case 3: ECHUNK(3) [[fallthrough]];
        case 2: ECHUNK(2) [[fallthrough]];
        case 1: ECHUNK(1) [[fallthrough]];
        case 0: ECHUNK(0) break;
        default: break;
      }
      const int d0 = db * 4;
      const float t0 = y0 - mk[d0 + 0], t1 = y1 - mk[d0 + 1];
      const float t2 = y2 - mk[d0 + 2], t3 = y3 - mk[d0 + 3];
      maha = fmaf(t0, t0, fmaf(t1, t1, fmaf(t2, t2, fmaf(t3, t3, maha))));
    }
    lp[lane][k] = kconst[k] - 0.5f * maha;
  }
  __syncthreads();
  if (w == 0) {
    float v[KC];
    float mx = -1e30f;
#pragma unroll
    for (int q = 0; q < KC; ++q) { v[q] = lp[lane][q]; mx = fmaxf(mx, v[q]); }
    float s = 0.0f;
#pragma unroll
    for (int q = 0; q < KC; ++q) { v[q] = expf(v[q] - mx); s += v[q]; }
    const float inv = 1.0f / s;
    float4* zr = (float4*)(Z + (size_t)row * KC);
#pragma unroll
    for (int q = 0; q < KC / 4; ++q)
      zr[q] = make_float4(v[4 * q] * inv, v[4 * q + 1] * inv,
                          v[4 * q + 2] * inv, v[4 * q + 3] * inv);
  }
}

// ---------------------------------------------------------------------------
// gram: partial G_k = sum_n z[n][k] * x_n x_n^T over n-chunk, plus s,tw.
// 1 wave/block; lane = local d; 32-col e-tile in regs; x[e-tile] scalar.
// Tiles: (dh,eq): 0:(0,0) 1:(0,1) 2:(1,0) 3:(1,1) 4:(1,2) 5:(1,3)
// (upper-right quadrant skipped; restored by symmetry in finalize_cov)
// ---------------------------------------------------------------------------
__global__ __launch_bounds__(64) void gram_kernel(
    const float* __restrict__ X, const float* __restrict__ Z,
    float* __restrict__ Gp, float* __restrict__ sp, float* __restrict__ twp)
{
  const int k = blockIdx.x;
  const int tile = blockIdx.y;
  const int ch = blockIdx.z;
  const int dh = tile >= 2 ? 1 : 0;
  const int eq = dh ? tile - 2 : tile;
  const int lane = threadIdx.x;
  const int d = dh * 64 + lane;
  const int e0 = eq * 32;
  const int n0 = ch * CHUNK;

  float G[32];
#pragma unroll
  for (int e = 0; e < 32; ++e) G[e] = 0.0f;
  float sacc = 0.0f, twacc = 0.0f;

#pragma unroll 2
  for (int n = n0; n < n0 + CHUNK; ++n) {
    const float zv = Z[(size_t)n * KC + k];                   // uniform -> s_load
    const float xd = X[(size_t)n * DIM + d];                  // coalesced vector
    const float* __restrict__ xs = X + (size_t)n * DIM + e0;  // uniform -> s_load
    const float u = zv * xd;
#pragma unroll
    for (int e = 0; e < 32; ++e) G[e] = fmaf(u, xs[e], G[e]);
    sacc += u;
    twacc += zv;
  }

  float* gout = Gp + (((size_t)ch * KC + k) * NTILES + tile) * 2048;
#pragma unroll
  for (int e = 0; e < 32; ++e) gout[e * 64 + lane] = G[e];    // [e_local][d_local]
  if (eq == 0) {
    sp[((size_t)ch * KC + k) * DIM + d] = sacc;
    if (tile == 0 && lane == 0) twp[ch * KC + k] = twacc;
  }
}

// stage-10 M-step needs only means: first moments without the Gram
__global__ __launch_bounds__(128) void moment_kernel(
    const float* __restrict__ X, const float* __restrict__ Z,
    float* __restrict__ sp, float* __restrict__ twp)
{
  const int k = blockIdx.x;
  const int ch = blockIdx.y;
  const int d = threadIdx.x;
  const int n0 = ch * CHUNK;
  float s = 0.0f, tw = 0.0f;
#pragma unroll 4
  for (int n = n0; n < n0 + CHUNK; ++n) {
    const float zv = Z[(size_t)n * KC + k];
    s = fmaf(zv, X[(size_t)n * DIM + d], s);
    tw += zv;
  }
  sp[((size_t)ch * KC + k) * DIM + d] = s;
  if (d == 0) twp[ch * KC + k] = tw;
}

__global__ __launch_bounds__(256) void reduce_means_kernel(
    const float* __restrict__ sp, const float* __restrict__ twp,
    float* __restrict__ means, float* __restrict__ tw_out)
{
  const int idx = blockIdx.x * 256 + threadIdx.x;  // k*128 + d
  const int k = idx >> 7;
  float tw = 0.0f;
#pragma unroll
  for (int c = 0; c < NCH; ++c) tw += twp[c * KC + k];
  float s = 0.0f;
  for (int c = 0; c < NCH; ++c) s += sp[(size_t)c * KC * DIM + idx];
  means[idx] = s / (tw + EPS_C);
  if ((idx & 127) == 0) tw_out[k] = tw;
}

// cov = G/(tw+eps) - ((tw+2eps)/(tw+eps)) * mu mu^T   (exact expansion of
// sum_n z (x-mu')(x-mu')^T / (tw+eps) with mu' = s/(tw+eps))
__global__ __launch_bounds__(256) void finalize_cov_kernel(
    const float* __restrict__ Gp, const float* __restrict__ means,
    const float* __restrict__ tw_in, float* __restrict__ covs)
{
  const int idx = blockIdx.x * 256 + threadIdx.x;  // k*16384 + d*128 + e
  const int k = idx >> 14;
  const int d = (idx >> 7) & 127;
  const int e = idx & 127;
  const int a = d >= e ? d : e;
  const int b = d >= e ? e : d;
  const int tile = (a >> 6) ? (2 + (b >> 5)) : (b >> 5);
  const int dl = a & 63, el = b & 31;
  float g = 0.0f;
  for (int c = 0; c < NCH; ++c)
    g += Gp[(((size_t)c * KC + k) * NTILES + tile) * 2048 + el * 64 + dl];
  const float tw = tw_in[k];
  const float denom = tw + EPS_C;
  const float md = means[k * DIM + d], me = means[k * DIM + e];
  covs[idx] = g / denom - ((tw + 2.0f * EPS_C) / denom) * md * me;
}

__global__ __launch_bounds__(256) void out_kernel(
    const float* __restrict__ X, const float* __restrict__ Z,
    const float* __restrict__ means, float* __restrict__ out)
{
  const int i4 = blockIdx.x * 256 + threadIdx.x;  // float4 index
  const int n = i4 >> 5;
  const int q = i4 & 31;
  float4 acc = ((const float4*)X)[i4];
  const float* zr = Z + (size_t)n * KC;
#pragma unroll
  for (int k = 0; k < KC; ++k) {
    const float zk = BETA_C * zr[k];
    const float4 mu = ((const float4*)means)[k * 32 + q];
    acc.x = fmaf(zk, mu.x, acc.x);
    acc.y = fmaf(zk, mu.y, acc.y);
    acc.z = fmaf(zk, mu.z, acc.z);
    acc.w = fmaf(zk, mu.w, acc.w);
  }
  ((float4*)out)[i4] = acc;
}

// ---------------------------------------------------------------------------
extern "C" void kernel_launch(void* const* d_in, const int* in_sizes, int n_in,
                              void* d_out, int out_size, void* d_ws, size_t ws_size,
                              hipStream_t stream)
{
  const float* X = (const float*)d_in[0];       // [65536,128]
  const float* means0 = (const float*)d_in[1];  // [16,128]
  const float* covs0 = (const float*)d_in[2];   // [16,128,128]
  float* out = (float*)d_out;                   // [65536,128]
  float* Zout = out + (size_t)NPTS * DIM;       // [65536,16] second output

  // workspace layout (floats); total 6,885,920 floats = 26.3 MiB
  float* ws = (float*)d_ws;
  float* covs_cur  = ws;                  // 262144
  float* W4        = covs_cur + 262144;   // 262144
  float* mvec      = W4 + 262144;         // 2048
  float* kconst    = mvec + 2048;         // 16
  float* tw        = kconst + 16;         // 16
  float* means_cur = tw + 16;             // 2048
  float* sp        = means_cur + 2048;    // 65536
  float* twp       = sp + 65536;          // 512
  float* Gp        = twp + 512;           // 32*16*6*2048 = 6291456

  const int prep_lds = 37312 * 4;  // 149,248 B dynamic LDS
  (void)hipFuncSetAttribute((const void*)prep_kernel,
      hipFuncAttributeMaxDynamicSharedMemorySize, prep_lds);

  for (int s = 0; s < STAGES; ++s) {
    const float* cs = (s == 0) ? covs0 : covs_cur;
    const float* ms = (s == 0) ? means0 : means_cur;
    prep_kernel<<<KC, 256, prep_lds, stream>>>(cs, ms, W4, mvec, kconst);
    estep_kernel<<<NPTS / 64, 128, 0, stream>>>(X, W4, mvec, kconst, Zout);
    if (s < STAGES - 1)
      gram_kernel<<<dim3(KC, NTILES, NCH), 64, 0, stream>>>(X, Zout, Gp, sp, twp);
    else
      moment_kernel<<<dim3(KC, NCH), 128, 0, stream>>>(X, Zout, sp, twp);
    reduce_means_kernel<<<8, 256, 0, stream>>>(sp, twp, means_cur, tw);
    if (s < STAGES - 1)
      finalize_cov_kernel<<<KC * DIM * DIM / 256, 256, 0, stream>>>(
          Gp, means_cur, tw, covs_cur);
  }
  out_kernel<<<(NPTS * DIM / 4) / 256, 256, 0, stream>>>(X, Zout, means_cur, out);
}